// Round 14
// baseline (310.314 us; speedup 1.0000x reference)
//
#include <hip/hip_runtime.h>
#include <hip/hip_fp16.h>

#define TPB 256
#define CHUNK 1024   // elements per scan block (256 threads x 4)
#define EPB 4096     // edges per partition block
#define CSHIFT 9     // coarse bucket = 512 nodes (dst_local fits 9 bits)

typedef _Float16 half8 __attribute__((ext_vector_type(8)));
typedef float    f32x4 __attribute__((ext_vector_type(4)));

// ---------------- scan A: per-chunk exclusive scan + chunk totals ----------------

__global__ __launch_bounds__(256) void scanA_kernel(const int* __restrict__ cnt,
                                                    int* __restrict__ row_ptr,
                                                    int* __restrict__ chunk_sums, int n) {
    __shared__ int ls[256];
    const int t    = threadIdx.x;
    const int base = blockIdx.x * CHUNK;
    const int idx  = base + t * 4;
    int4 v = make_int4(0, 0, 0, 0);
    if (idx + 3 < n) v = *(const int4*)(cnt + idx);
    else {
        if (idx + 0 < n) v.x = cnt[idx + 0];
        if (idx + 1 < n) v.y = cnt[idx + 1];
        if (idx + 2 < n) v.z = cnt[idx + 2];
        if (idx + 3 < n) v.w = cnt[idx + 3];
    }
    int s0 = v.x, s1 = s0 + v.y, s2 = s1 + v.z, s3 = s2 + v.w;
    ls[t] = s3;
    __syncthreads();
    for (int off = 1; off < 256; off <<= 1) {
        int xv = (t >= off) ? ls[t - off] : 0;
        __syncthreads();
        ls[t] += xv;
        __syncthreads();
    }
    int excl = (t == 0) ? 0 : ls[t - 1];
    if (idx + 0 < n) row_ptr[idx + 0] = excl;
    if (idx + 1 < n) row_ptr[idx + 1] = excl + s0;
    if (idx + 2 < n) row_ptr[idx + 2] = excl + s1;
    if (idx + 3 < n) row_ptr[idx + 3] = excl + s2;
    if (t == 255) chunk_sums[blockIdx.x] = ls[255];
}

// scan C (fused with B): each block redundantly scans the <=256 chunk totals
// in LDS, then applies its own exclusive offset. One dispatch instead of two.

__global__ __launch_bounds__(256) void scanC_kernel(int* __restrict__ row_ptr,
                                                    const int* __restrict__ chunk_sums,
                                                    int n, int nch) {
    __shared__ int ls[256];
    const int t = threadIdx.x;
    ls[t] = (t < nch) ? chunk_sums[t] : 0;
    __syncthreads();
    for (int off = 1; off < 256; off <<= 1) {
        int xv = (t >= off) ? ls[t - off] : 0;
        __syncthreads();
        ls[t] += xv;
        __syncthreads();
    }
    const int boff = (blockIdx.x == 0) ? 0 : ls[blockIdx.x - 1];
    const int base = blockIdx.x * CHUNK;
    for (int k = t; k < CHUNK; k += 256) {
        int i = base + k;
        if (i < n) row_ptr[i] += boff;
    }
}

// ---------------- CSR build: deterministic counting partition ----------------

__global__ __launch_bounds__(256) void hist_kernel(const int* __restrict__ dst,
                                                   int* __restrict__ hist_g,
                                                   int e, int nbc, int nblk) {
    __shared__ int hs[256];
    const int t = threadIdx.x;
    if (t < nbc) hs[t] = 0;
    __syncthreads();
    const int e0  = blockIdx.x * EPB;
    const int lim = min(e0 + EPB, e);
    for (int i = e0 + t; i < lim; i += 256)
        atomicAdd(&hs[dst[i] >> CSHIFT], 1);
    __syncthreads();
    if (t < nbc) hist_g[t * nblk + blockIdx.x] = hs[t];
}

// pairs entries PACKED 32-bit: (dst_local << 17) | src  (src<2^17, dlocal<2^9)
__global__ __launch_bounds__(256) void partition_kernel(const int* __restrict__ src,
                                                        const int* __restrict__ dst,
                                                        const int* __restrict__ hist_scan,
                                                        int* __restrict__ pairs,
                                                        int e, int nbc, int nblk) {
    __shared__ int  hs[256];
    __shared__ int  lscan[256];
    __shared__ int  lfill[256];
    __shared__ int  base_s[256];
    __shared__ int  ls[256];
    __shared__ int2 sp[EPB];   // 32 KB staging
    const int t = threadIdx.x;
    if (t < nbc) { hs[t] = 0; lfill[t] = 0; }
    __syncthreads();
    const int e0  = blockIdx.x * EPB;
    const int lim = min(e0 + EPB, e);
    for (int i = e0 + t; i < lim; i += 256)
        atomicAdd(&hs[dst[i] >> CSHIFT], 1);
    __syncthreads();
    ls[t] = (t < nbc) ? hs[t] : 0;
    __syncthreads();
    for (int off = 1; off < 256; off <<= 1) {
        int xv = (t >= off) ? ls[t - off] : 0;
        __syncthreads();
        ls[t] += xv;
        __syncthreads();
    }
    if (t < nbc) {
        lscan[t]  = (t == 0) ? 0 : ls[t - 1];
        base_s[t] = hist_scan[t * nblk + blockIdx.x];
    }
    __syncthreads();
    for (int i = e0 + t; i < lim; i += 256) {
        int d = dst[i];
        int b = d >> CSHIFT;
        int r = atomicAdd(&lfill[b], 1);
        sp[lscan[b] + r] = make_int2(src[i], d);
    }
    __syncthreads();
    const int cnt = lim - e0;
    for (int i = t; i < cnt; i += 256) {
        int2 pr = sp[i];
        int  b  = pr.y >> CSHIFT;
        pairs[base_s[b] + (i - lscan[b])] = pr.x | ((pr.y & 511) << 17);
    }
}

// One block per 512-node bucket: per-node count + 2-per-thread LDS scan, then
// write row_ptr, dinv, and place csr_src. No global atomics anywhere.
__global__ __launch_bounds__(256) void bucket_finalize_kernel(const int* __restrict__ pairs,
                                                              const int* __restrict__ hist_scan,
                                                              int* __restrict__ row_ptr,
                                                              float* __restrict__ dinv,
                                                              int* __restrict__ csr_src,
                                                              int n, int e, int nbc, int nblk) {
    __shared__ int cnt_s[512];
    __shared__ int fill[512];
    __shared__ int ls[256];
    const int b   = blockIdx.x;
    const int nb0 = b << CSHIFT;
    const int t   = threadIdx.x;
    const int r0  = hist_scan[b * nblk];                       // bucket start
    const int r1  = (b + 1 < nbc) ? hist_scan[(b + 1) * nblk] : e;
    cnt_s[t] = 0; cnt_s[t + 256] = 0;
    __syncthreads();
    for (int i = r0 + t; i < r1; i += 256)
        atomicAdd(&cnt_s[pairs[i] >> 17], 1);
    __syncthreads();
    int v0 = cnt_s[2 * t];
    int v1 = cnt_s[2 * t + 1];
    ls[t] = v0 + v1;
    __syncthreads();
    for (int off = 1; off < 256; off <<= 1) {
        int xv = (t >= off) ? ls[t - off] : 0;
        __syncthreads();
        ls[t] += xv;
        __syncthreads();
    }
    int excl = (t == 0) ? 0 : ls[t - 1];
    int off0 = r0 + excl;
    int off1 = off0 + v0;
    int node0 = nb0 + 2 * t;
    int node1 = nb0 + 2 * t + 1;
    if (node0 < n) {
        row_ptr[node0] = off0;
        dinv[node0]    = rsqrtf((float)(v0 + 1));   // +1 self-loop
    }
    if (node1 < n) {
        row_ptr[node1] = off1;
        dinv[node1]    = rsqrtf((float)(v1 + 1));
    }
    fill[2 * t]     = off0;
    fill[2 * t + 1] = off1;
    __syncthreads();
    for (int i = r0 + t; i < r1; i += 256) {
        int pr = pairs[i];
        int p  = atomicAdd(&fill[pr >> 17], 1);
        csr_src[p] = pr & 0x1FFFF;
    }
    if (b == 0 && t == 0) row_ptr[n] = e;
}

// ---------------- dense transform via MFMA: HS(fp16) = dinv[row] * (relu?)(X) @ W ----------------
// R11-R13-proven. A[m=lane&15][k=quad*8+j]; C/D: col=lane&15, row=quad*4+reg.

template <int M, bool RELU, typename XT>
__global__ __launch_bounds__(256) void gemm_mfma_kernel(const XT* __restrict__ X,
                                                        const float* __restrict__ W,
                                                        const float* __restrict__ dinv,
                                                        __half* __restrict__ H, int nrows) {
    constexpr int NC = M / 16;                 // col-tiles: 8 (M=128) / 4 (M=64)
    __shared__ __align__(16) _Float16 Wf[NC * 4 * 64 * 8];   // 32 KB / 16 KB

    const int tid = threadIdx.x;

    for (int f = tid; f < NC * 4 * 64; f += 256) {
        int c    = f >> 8;
        int i    = (f >> 6) & 3;
        int lane = f & 63;
        int quad = lane >> 4, n = lane & 15;
        const float* wp = W + (size_t)(i * 32 + quad * 8) * M + c * 16 + n;
        half8 hv;
#pragma unroll
        for (int j = 0; j < 8; ++j) hv[j] = (_Float16)wp[(size_t)j * M];
        ((half8*)Wf)[f] = hv;
    }
    __syncthreads();

    const int  wave = tid >> 6, lane = tid & 63;
    const int  quad = lane >> 4, n16 = lane & 15;
    const long rowbase = (long)blockIdx.x * 64 + wave * 16;

    long arow = rowbase + n16;
    const XT* xrow = X + (size_t)(arow < nrows ? arow : 0) * 128;
    half8 a[4];
    if constexpr (sizeof(XT) == 4) {   // fp32 input
        const float4* xr = (const float4*)xrow;
#pragma unroll
        for (int i = 0; i < 4; ++i) {
            float4 x0 = xr[i * 8 + quad * 2];
            float4 x1 = xr[i * 8 + quad * 2 + 1];
            if (RELU) {
                x0.x = fmaxf(x0.x, 0.f); x0.y = fmaxf(x0.y, 0.f);
                x0.z = fmaxf(x0.z, 0.f); x0.w = fmaxf(x0.w, 0.f);
                x1.x = fmaxf(x1.x, 0.f); x1.y = fmaxf(x1.y, 0.f);
                x1.z = fmaxf(x1.z, 0.f); x1.w = fmaxf(x1.w, 0.f);
            }
            half8 hv;
            hv[0] = (_Float16)x0.x; hv[1] = (_Float16)x0.y;
            hv[2] = (_Float16)x0.z; hv[3] = (_Float16)x0.w;
            hv[4] = (_Float16)x1.x; hv[5] = (_Float16)x1.y;
            hv[6] = (_Float16)x1.z; hv[7] = (_Float16)x1.w;
            a[i] = hv;
        }
    } else {                           // fp16 input (out1)
        const half8* xr = (const half8*)xrow;
#pragma unroll
        for (int i = 0; i < 4; ++i) {
            half8 hv = xr[i * 4 + quad];
            if (RELU) {
#pragma unroll
                for (int j = 0; j < 8; ++j)
                    hv[j] = (hv[j] > (_Float16)0) ? hv[j] : (_Float16)0;
            }
            a[i] = hv;
        }
    }

    float dv[4];
#pragma unroll
    for (int r = 0; r < 4; ++r) {
        long orow = rowbase + quad * 4 + r;
        dv[r] = (orow < nrows) ? dinv[orow] : 0.f;
    }

    for (int c = 0; c < NC; ++c) {
        f32x4 acc = {0.f, 0.f, 0.f, 0.f};
#pragma unroll
        for (int i = 0; i < 4; ++i) {
            half8 b = ((const half8*)Wf)[(c * 4 + i) * 64 + lane];
            acc = __builtin_amdgcn_mfma_f32_16x16x32_f16(a[i], b, acc, 0, 0, 0);
        }
#pragma unroll
        for (int r = 0; r < 4; ++r) {
            long orow = rowbase + quad * 4 + r;
            if (orow < nrows)
                H[orow * M + c * 16 + n16] = __float2half(acc[r] * dv[r]);
        }
    }
}

// ---------------- pull aggregation layer 1: out1(fp16) = b + dinv_d*(hs_d + sum hs_s) ----------------
// R12/R13-proven 16/4/1 cascade; fp16 store.

__global__ __launch_bounds__(TPB) void agg_pull128_kernel(const __half* __restrict__ hs,
                                                          const int* __restrict__ csr_src,
                                                          const int* __restrict__ row_ptr,
                                                          const float* __restrict__ dinv,
                                                          const float* __restrict__ bias,
                                                          __half* __restrict__ out, int n) {
    const int node = blockIdx.x * (TPB / 64) + (threadIdx.x >> 6);
    const int lane = threadIdx.x & 63;
    if (node >= n) return;
    const int beg = row_ptr[node];
    const int end = row_ptr[node + 1];

    const __half2* hp = (const __half2*)hs;
    float2 a[16];
#pragma unroll
    for (int r = 1; r < 16; ++r) a[r] = make_float2(0.f, 0.f);
    a[0] = __half22float2(hp[(long)node * 64 + lane]);  // self-loop term
    for (int base = beg; base < end; base += 64) {
        int m = end - base; if (m > 64) m = 64;
        int idx = (lane < m) ? csr_src[base + lane] : 0;
        int j = 0;
        for (; j + 16 <= m; j += 16) {
#pragma unroll
            for (int r = 0; r < 16; ++r) {
                int s = __shfl(idx, j + r);
                float2 v = __half22float2(hp[(long)s * 64 + lane]);
                a[r].x += v.x; a[r].y += v.y;
            }
        }
        for (; j + 4 <= m; j += 4) {
#pragma unroll
            for (int r = 0; r < 4; ++r) {
                int s = __shfl(idx, j + r);
                float2 v = __half22float2(hp[(long)s * 64 + lane]);
                a[r].x += v.x; a[r].y += v.y;
            }
        }
        for (; j < m; ++j) {
            int s = __shfl(idx, j);
            float2 v = __half22float2(hp[(long)s * 64 + lane]);
            a[0].x += v.x; a[0].y += v.y;
        }
    }
#pragma unroll
    for (int r = 8; r < 16; ++r) { a[r - 8].x += a[r].x; a[r - 8].y += a[r].y; }
#pragma unroll
    for (int r = 4; r < 8; ++r) { a[r - 4].x += a[r].x; a[r - 4].y += a[r].y; }
    float  di = dinv[node];
    float2 bv = ((const float2*)bias)[lane];
    float ox = bv.x + di * ((a[0].x + a[1].x) + (a[2].x + a[3].x));
    float oy = bv.y + di * ((a[0].y + a[1].y) + (a[2].y + a[3].y));
    ((__half2*)out)[(long)node * 64 + lane] = __floats2half2_rn(ox, oy);
}

// ---------------- pull aggregation layer 2: out(fp32) = b + dinv_d*(hs_d + sum hs_s) ----------------
// R13-proven: 2 edges per wave; divergence-safe tail.

__global__ __launch_bounds__(TPB) void agg_pull64_kernel(const __half* __restrict__ hs,
                                                         const int* __restrict__ csr_src,
                                                         const int* __restrict__ row_ptr,
                                                         const float* __restrict__ dinv,
                                                         const float* __restrict__ bias,
                                                         float* __restrict__ out, int n) {
    const int node = blockIdx.x * (TPB / 64) + (threadIdx.x >> 6);
    const int lane = threadIdx.x & 63;
    if (node >= n) return;
    const int half = lane >> 5;   // which edge of the pair
    const int sl   = lane & 31;   // half2 column index within row
    const int beg = row_ptr[node];
    const int end = row_ptr[node + 1];
    const __half2* hp = (const __half2*)hs;

    float2 a[8];
#pragma unroll
    for (int r = 0; r < 8; ++r) a[r] = make_float2(0.f, 0.f);

    for (int base = beg; base < end; base += 64) {
        int m = end - base; if (m > 64) m = 64;
        int idx = (lane < m) ? csr_src[base + lane] : 0;
        int j = 0;
        for (; j + 16 <= m; j += 16) {
#pragma unroll
            for (int r = 0; r < 8; ++r) {
                int s = __shfl(idx, j + 2 * r + half);
                float2 v = __half22float2(hp[(long)s * 32 + sl]);
                a[r].x += v.x; a[r].y += v.y;
            }
        }
        for (; j + 2 <= m; j += 2) {
            int s = __shfl(idx, j + half);
            float2 v = __half22float2(hp[(long)s * 32 + sl]);
            a[0].x += v.x; a[0].y += v.y;
        }
        if (j < m) {  // single leftover edge; uniform branch, shfl by all lanes
            int s = __shfl(idx, j);
            float2 v = __half22float2(hp[(long)s * 32 + sl]);
            if (half == 0) { a[0].x += v.x; a[0].y += v.y; }
        }
    }
#pragma unroll
    for (int r = 4; r < 8; ++r) { a[r - 4].x += a[r].x; a[r - 4].y += a[r].y; }
    float2 acc;
    acc.x = (a[0].x + a[1].x) + (a[2].x + a[3].x);
    acc.y = (a[0].y + a[1].y) + (a[2].y + a[3].y);
    acc.x += __shfl(acc.x, lane ^ 32);
    acc.y += __shfl(acc.y, lane ^ 32);
    if (half == 0) {
        float2 sv = __half22float2(hp[(long)node * 32 + sl]);  // self-loop
        float  di = dinv[node];
        float2 bv = ((const float2*)bias)[sl];
        float2 o;
        o.x = bv.x + di * (acc.x + sv.x);
        o.y = bv.y + di * (acc.y + sv.y);
        ((float2*)out)[(long)node * 32 + sl] = o;
    }
}

// ---------------- launcher ----------------

extern "C" void kernel_launch(void* const* d_in, const int* in_sizes, int n_in,
                              void* d_out, int out_size, void* d_ws, size_t ws_size,
                              hipStream_t stream) {
    const float* x  = (const float*)d_in[0];
    const int*   ei = (const int*)d_in[1];   // int32 on the wire
    const float* W1 = (const float*)d_in[2];
    const float* b1 = (const float*)d_in[3];
    const float* W2 = (const float*)d_in[4];
    const float* b2 = (const float*)d_in[5];
    float* out = (float*)d_out;

    const int N = in_sizes[0] / 128;   // 100000
    const int E = in_sizes[1] / 2;     // 1600000
    const int* srcv = ei;
    const int* dstv = ei + E;

    const int NBC    = (N + 511) >> CSHIFT;           // 196 coarse buckets
    const int NBLK_E = (E + EPB - 1) / EPB;           // 391 edge blocks
    const int HLEN   = NBC * NBLK_E;                  // 76,636
    const int NCHH   = (HLEN + CHUNK - 1) / CHUNK;    // 75

    // workspace layout
    char* p = (char*)d_ws;
    int*    row_ptr    = (int*)p;           p += ((size_t)N + 64) * 4;
    int*    chunk_sums = (int*)p;           p += 1024;
    int*    hist       = (int*)p;           p += ((size_t)HLEN + 64) * 4;
    int*    csr_src    = (int*)p;           p += (size_t)E * 4;
    float*  dinv       = (float*)p;         p += ((size_t)N + 64) * 4;
    __half* hs1        = (__half*)p;        p += (size_t)N * 128 * 2;
    __half* out1       = (__half*)p;        p += (size_t)N * 128 * 2;
    int*    pairs      = (int*)out1;        // alias: out1 dead until after CSR build
    __half* hs2        = hs1;               // hs1 dead once out1 complete

    // ---- CSR build + normalization (histogram -> scan -> partition -> finalize) ----
    hist_kernel<<<NBLK_E, 256, 0, stream>>>(dstv, hist, E, NBC, NBLK_E);
    scanA_kernel<<<NCHH, 256, 0, stream>>>(hist, hist, chunk_sums, HLEN);  // in-place safe
    scanC_kernel<<<NCHH, 256, 0, stream>>>(hist, chunk_sums, HLEN, NCHH);  // fused B+C
    partition_kernel<<<NBLK_E, 256, 0, stream>>>(srcv, dstv, hist, pairs, E, NBC, NBLK_E);
    bucket_finalize_kernel<<<NBC, 256, 0, stream>>>(pairs, hist, row_ptr, dinv, csr_src,
                                                    N, E, NBC, NBLK_E);

    // ---- layer 1: MFMA GEMM (fp32 in, fp16 out), agg -> fp16 out1 ----
    gemm_mfma_kernel<128, false, float><<<(N + 63) / 64, 256, 0, stream>>>(x, W1, dinv, hs1, N);
    agg_pull128_kernel<<<(N + 3) / 4, TPB, 0, stream>>>(hs1, csr_src, row_ptr, dinv, b1, out1, N);

    // ---- layer 2: MFMA GEMM (fp16 in w/ fused ReLU), agg -> fp32 d_out ----
    gemm_mfma_kernel<64, true, _Float16><<<(N + 63) / 64, 256, 0, stream>>>(
        (const _Float16*)out1, W2, dinv, hs2, N);
    agg_pull64_kernel<<<(N + 3) / 4, TPB, 0, stream>>>(hs2, csr_src, row_ptr, dinv, b2, out, N);
}